// Round 1
// baseline (2895.566 us; speedup 1.0000x reference)
//
#include <hip/hip_runtime.h>

constexpr int CH = 128;      // IN_CH == OUT_CH == 128

// ---------- degree kernels ----------
__global__ __launch_bounds__(256) void k_deg_init(float* __restrict__ deg, int N) {
    int i = blockIdx.x * blockDim.x + threadIdx.x;
    if (i < N) deg[i] = 1.0f;   // self-loop contributes 1 to every node
}

__global__ __launch_bounds__(256) void k_deg_accum(const int* __restrict__ dst,
                                                   float* __restrict__ deg, int E) {
    int e = blockIdx.x * blockDim.x + threadIdx.x;
    if (e < E) atomicAdd(&deg[dst[e]], 1.0f);
}

__global__ __launch_bounds__(256) void k_dinv(float* __restrict__ deg, int N) {
    int i = blockIdx.x * blockDim.x + threadIdx.x;
    if (i < N) deg[i] = rsqrtf(deg[i]);   // deg >= 1 always (self-loop)
}

// ---------- XW = x @ W  (fp32, VALU; W staged in LDS) ----------
// block: 256 threads = 8 rows (ty) x 32 col-groups (tx, float4 each)
__global__ __launch_bounds__(256) void k_gemm(const float* __restrict__ x,
                                              const float* __restrict__ W,
                                              float* __restrict__ xw, int N) {
    __shared__ float Ws[CH][CH];   // 64 KiB
    __shared__ float xs[8][CH];    // 4 KiB
    int t = threadIdx.x;

    // cooperative load of W (4096 float4, 16 per thread)
    {
        const float4* W4 = (const float4*)W;
        float4* Ws4 = (float4*)(&Ws[0][0]);
        #pragma unroll
        for (int i = 0; i < 16; ++i) Ws4[t + i * 256] = W4[t + i * 256];
    }
    int row0 = blockIdx.x * 8;
    // cooperative load of 8 x-rows (256 float4, 1 per thread)
    {
        int r  = t >> 5;
        int c4 = t & 31;
        int row = row0 + r;
        float4 v = make_float4(0.f, 0.f, 0.f, 0.f);
        if (row < N) v = ((const float4*)(x + (size_t)row * CH))[c4];
        ((float4*)(&xs[r][0]))[c4] = v;
    }
    __syncthreads();

    int ty = t >> 5;          // row within block
    int tx = t & 31;          // float4 column group
    int row = row0 + ty;
    float4 acc = make_float4(0.f, 0.f, 0.f, 0.f);
    #pragma unroll
    for (int k = 0; k < CH; ++k) {
        float  xv = xs[ty][k];                       // broadcast (2 addrs/wave)
        float4 w  = ((const float4*)(&Ws[k][0]))[tx];
        acc.x = fmaf(xv, w.x, acc.x);
        acc.y = fmaf(xv, w.y, acc.y);
        acc.z = fmaf(xv, w.z, acc.z);
        acc.w = fmaf(xv, w.w, acc.w);
    }
    if (row < N) ((float4*)(xw + (size_t)row * CH))[tx] = acc;
}

// ---------- out = xw * dinv^2 + b  (self-loop message + bias) ----------
__global__ __launch_bounds__(256) void k_self_init(const float* __restrict__ xw,
                                                   const float* __restrict__ dinv,
                                                   const float* __restrict__ bias,
                                                   float* __restrict__ out, int n4) {
    int idx = blockIdx.x * blockDim.x + threadIdx.x;   // over N*CH/4
    if (idx >= n4) return;
    int node = idx >> 5;          // CH/4 == 32 float4 per node
    int c4   = idx & 31;
    float di = dinv[node];
    float s  = di * di;
    float4 v  = ((const float4*)xw)[idx];
    float4 bb = ((const float4*)bias)[c4];
    float4 o;
    o.x = fmaf(v.x, s, bb.x);
    o.y = fmaf(v.y, s, bb.y);
    o.z = fmaf(v.z, s, bb.z);
    o.w = fmaf(v.w, s, bb.w);
    ((float4*)out)[idx] = o;
}

// ---------- edge scatter: 32 lanes per edge, float4 per lane ----------
__global__ __launch_bounds__(256) void k_scatter(const int* __restrict__ src,
                                                 const int* __restrict__ dst,
                                                 const float* __restrict__ xw,
                                                 const float* __restrict__ dinv,
                                                 float* __restrict__ out, int E) {
    long long tid = (long long)blockIdx.x * blockDim.x + threadIdx.x;
    int e  = (int)(tid >> 5);
    int c4 = (int)(tid & 31);
    if (e >= E) return;
    int s = src[e];
    int d = dst[e];
    float norm = dinv[s] * dinv[d];
    float4 v = ((const float4*)(xw + (size_t)s * CH))[c4];
    float* o = out + (size_t)d * CH + c4 * 4;
    atomicAdd(o + 0, v.x * norm);
    atomicAdd(o + 1, v.y * norm);
    atomicAdd(o + 2, v.z * norm);
    atomicAdd(o + 3, v.w * norm);
}

// ---------- in-place ReLU ----------
__global__ __launch_bounds__(256) void k_relu(float* __restrict__ out, int n4) {
    int idx = blockIdx.x * blockDim.x + threadIdx.x;
    if (idx >= n4) return;
    float4 v = ((float4*)out)[idx];
    v.x = fmaxf(v.x, 0.f);
    v.y = fmaxf(v.y, 0.f);
    v.z = fmaxf(v.z, 0.f);
    v.w = fmaxf(v.w, 0.f);
    ((float4*)out)[idx] = v;
}

extern "C" void kernel_launch(void* const* d_in, const int* in_sizes, int n_in,
                              void* d_out, int out_size, void* d_ws, size_t ws_size,
                              hipStream_t stream) {
    const float* x  = (const float*)d_in[0];
    const int*   ei = (const int*)d_in[1];     // int32 per harness convention
    const float* W  = (const float*)d_in[2];
    const float* b  = (const float*)d_in[3];

    int N = in_sizes[0] / CH;
    int E = in_sizes[1] / 2;
    const int* src = ei;
    const int* dst = ei + E;

    float* out = (float*)d_out;
    float* xw  = (float*)d_ws;                       // N*CH floats (51.2 MB)
    float* deg = xw + (size_t)N * CH;                // N floats

    int n4 = N * CH / 4;

    k_deg_init <<<(N + 255) / 256, 256, 0, stream>>>(deg, N);
    k_deg_accum<<<(E + 255) / 256, 256, 0, stream>>>(dst, deg, E);
    k_dinv     <<<(N + 255) / 256, 256, 0, stream>>>(deg, N);
    k_gemm     <<<(N + 7) / 8,     256, 0, stream>>>(x, W, xw, N);
    k_self_init<<<(n4 + 255) / 256, 256, 0, stream>>>(xw, deg, b, out, n4);
    {
        long long threads = (long long)E * 32;
        int blocks = (int)((threads + 255) / 256);
        k_scatter<<<blocks, 256, 0, stream>>>(src, dst, xw, deg, out, E);
    }
    k_relu     <<<(n4 + 255) / 256, 256, 0, stream>>>(out, n4);
}

// Round 2
// 412.297 us; speedup vs baseline: 7.0230x; 7.0230x over previous
//
#include <hip/hip_runtime.h>

constexpr int CH = 128;      // IN_CH == OUT_CH == 128

// ---------- 1. histogram of dst ----------
__global__ __launch_bounds__(256) void k_count(const int* __restrict__ dst,
                                               int* __restrict__ cnt, int E) {
    int e = blockIdx.x * 256 + threadIdx.x;
    if (e < E) atomicAdd(&cnt[dst[e]], 1);
}

// ---------- 2. scan step A: per-block sums ----------
__global__ __launch_bounds__(256) void k_scanA(const int* __restrict__ cnt,
                                               int* __restrict__ bsum, int N) {
    __shared__ int s[256];
    int i = blockIdx.x * 256 + threadIdx.x;
    s[threadIdx.x] = (i < N) ? cnt[i] : 0;
    __syncthreads();
    for (int off = 128; off > 0; off >>= 1) {
        if (threadIdx.x < off) s[threadIdx.x] += s[threadIdx.x + off];
        __syncthreads();
    }
    if (threadIdx.x == 0) bsum[blockIdx.x] = s[0];
}

// ---------- 3. scan step B: exclusive scan of block sums (single block) ----------
__global__ __launch_bounds__(512) void k_scanB(int* __restrict__ bsum, int nb,
                                               int* __restrict__ row_ptr, int N, int E) {
    __shared__ int s[512];
    int t = threadIdx.x;
    int v = (t < nb) ? bsum[t] : 0;
    s[t] = v;
    __syncthreads();
    for (int off = 1; off < 512; off <<= 1) {
        int add = (t >= off) ? s[t - off] : 0;
        __syncthreads();
        s[t] += add;
        __syncthreads();
    }
    if (t < nb) bsum[t] = s[t] - v;     // exclusive
    if (t == 0) row_ptr[N] = E;
}

// ---------- 4. scan step C: per-element exclusive scan -> row_ptr; dinv ----------
__global__ __launch_bounds__(256) void k_scanC(const int* __restrict__ cnt,
                                               const int* __restrict__ bsum,
                                               int* __restrict__ row_ptr,
                                               float* __restrict__ dinv, int N) {
    __shared__ int s[256];
    int i = blockIdx.x * 256 + threadIdx.x;
    int t = threadIdx.x;
    int c = (i < N) ? cnt[i] : 0;
    s[t] = c;
    __syncthreads();
    for (int off = 1; off < 256; off <<= 1) {
        int add = (t >= off) ? s[t - off] : 0;
        __syncthreads();
        s[t] += add;
        __syncthreads();
    }
    if (i < N) {
        row_ptr[i] = bsum[blockIdx.x] + s[t] - c;          // exclusive scan
        dinv[i] = rsqrtf((float)c + 1.0f);                 // +1 self-loop
    }
}

// ---------- 5. fill CSR bins ----------
__global__ __launch_bounds__(256) void k_fill(const int* __restrict__ src,
                                              const int* __restrict__ dst,
                                              const int* __restrict__ row_ptr,
                                              int* __restrict__ cursor,
                                              int* __restrict__ eidx, int E) {
    int e = blockIdx.x * 256 + threadIdx.x;
    if (e >= E) return;
    int d = dst[e];
    int pos = row_ptr[d] + atomicAdd(&cursor[d], 1);
    eidx[pos] = src[e];
}

// ---------- 6. XW = x @ W  (fp32 VALU; W staged in LDS) ----------
__global__ __launch_bounds__(256) void k_gemm(const float* __restrict__ x,
                                              const float* __restrict__ W,
                                              float* __restrict__ xw, int N) {
    __shared__ float Ws[CH][CH];   // 64 KiB
    __shared__ float xs[8][CH];    // 4 KiB
    int t = threadIdx.x;
    {
        const float4* W4 = (const float4*)W;
        float4* Ws4 = (float4*)(&Ws[0][0]);
        #pragma unroll
        for (int i = 0; i < 16; ++i) Ws4[t + i * 256] = W4[t + i * 256];
    }
    int row0 = blockIdx.x * 8;
    {
        int r  = t >> 5;
        int c4 = t & 31;
        int row = row0 + r;
        float4 v = make_float4(0.f, 0.f, 0.f, 0.f);
        if (row < N) v = ((const float4*)(x + (size_t)row * CH))[c4];
        ((float4*)(&xs[r][0]))[c4] = v;
    }
    __syncthreads();
    int ty = t >> 5;
    int tx = t & 31;
    int row = row0 + ty;
    float4 acc = make_float4(0.f, 0.f, 0.f, 0.f);
    #pragma unroll
    for (int k = 0; k < CH; ++k) {
        float  xv = xs[ty][k];
        float4 w  = ((const float4*)(&Ws[k][0]))[tx];
        acc.x = fmaf(xv, w.x, acc.x);
        acc.y = fmaf(xv, w.y, acc.y);
        acc.z = fmaf(xv, w.z, acc.z);
        acc.w = fmaf(xv, w.w, acc.w);
    }
    if (row < N) ((float4*)(xw + (size_t)row * CH))[tx] = acc;
}

// ---------- 7. fused gather + self-loop + bias + ReLU ----------
// one 64-lane wave per destination node; float2 (8B) per lane over 128 ch
__global__ __launch_bounds__(256) void k_gather(const int* __restrict__ row_ptr,
                                                const int* __restrict__ eidx,
                                                const float* __restrict__ xw,
                                                const float* __restrict__ dinv,
                                                const float* __restrict__ bias,
                                                float* __restrict__ out, int N) {
    int n = blockIdx.x * 4 + (threadIdx.x >> 6);
    if (n >= N) return;
    int lane = threadIdx.x & 63;
    int beg = row_ptr[n];
    int end = row_ptr[n + 1];
    float2 acc = make_float2(0.f, 0.f);
    for (int p0 = beg; p0 < end; p0 += 64) {
        int m = end - p0; if (m > 64) m = 64;
        int   myi = (lane < m) ? eidx[p0 + lane] : 0;     // coalesced batch load
        float myn = (lane < m) ? dinv[myi] : 0.f;         // parallel gather
        for (int j = 0; j < m; ++j) {
            int   s  = __shfl(myi, j);
            float ns = __shfl(myn, j);
            float2 v = ((const float2*)(xw + (size_t)s * CH))[lane];
            acc.x = fmaf(v.x, ns, acc.x);
            acc.y = fmaf(v.y, ns, acc.y);
        }
    }
    float dn = dinv[n];
    float2 sv = ((const float2*)(xw + (size_t)n * CH))[lane];   // self-loop
    acc.x = fmaf(sv.x, dn, acc.x);
    acc.y = fmaf(sv.y, dn, acc.y);
    float2 bb = ((const float2*)bias)[lane];
    float2 o;
    o.x = fmaxf(fmaf(acc.x, dn, bb.x), 0.f);
    o.y = fmaxf(fmaf(acc.y, dn, bb.y), 0.f);
    ((float2*)(out + (size_t)n * CH))[lane] = o;
}

extern "C" void kernel_launch(void* const* d_in, const int* in_sizes, int n_in,
                              void* d_out, int out_size, void* d_ws, size_t ws_size,
                              hipStream_t stream) {
    const float* x  = (const float*)d_in[0];
    const int*   ei = (const int*)d_in[1];
    const float* W  = (const float*)d_in[2];
    const float* b  = (const float*)d_in[3];

    int N = in_sizes[0] / CH;
    int E = in_sizes[1] / 2;
    const int* src = ei;
    const int* dst = ei + E;
    float* out = (float*)d_out;

    // workspace layout
    float* xw      = (float*)d_ws;                       // N*CH floats
    int*   cnt     = (int*)(xw + (size_t)N * CH);        // N
    int*   cursor  = cnt + N;                            // N
    int*   row_ptr = cursor + N;                         // N+1
    float* dinv    = (float*)(row_ptr + N + 1);          // N
    int*   bsum    = (int*)(dinv + N);                   // 512
    int*   eidx    = bsum + 512;                         // E

    int nb = (N + 255) / 256;                            // 391 (<512)

    hipMemsetAsync(cnt, 0, (size_t)2 * N * sizeof(int), stream);   // cnt + cursor
    k_count<<<(E + 255) / 256, 256, 0, stream>>>(dst, cnt, E);
    k_scanA<<<nb, 256, 0, stream>>>(cnt, bsum, N);
    k_scanB<<<1, 512, 0, stream>>>(bsum, nb, row_ptr, N, E);
    k_scanC<<<nb, 256, 0, stream>>>(cnt, bsum, row_ptr, dinv, N);
    k_fill <<<(E + 255) / 256, 256, 0, stream>>>(src, dst, row_ptr, cursor, eidx, E);
    k_gemm <<<(N + 7) / 8, 256, 0, stream>>>(x, W, xw, N);
    k_gather<<<(N + 3) / 4, 256, 0, stream>>>(row_ptr, eidx, xw, dinv, b, out, N);
}

// Round 3
// 330.185 us; speedup vs baseline: 8.7695x; 1.2487x over previous
//
#include <hip/hip_runtime.h>

constexpr int CH = 128;      // IN_CH == OUT_CH == 128

__device__ __forceinline__ unsigned short f2bf(float f) {
    unsigned u = __float_as_uint(f);
    u = (u + 0x7fffu + ((u >> 16) & 1u)) >> 16;   // RTN-even
    return (unsigned short)u;
}

// ---------- 1. histogram of dst ----------
__global__ __launch_bounds__(256) void k_count(const int* __restrict__ dst,
                                               int* __restrict__ cnt, int E) {
    int e = blockIdx.x * 256 + threadIdx.x;
    if (e < E) atomicAdd(&cnt[dst[e]], 1);
}

// ---------- 2. scan step A: per-block sums ----------
__global__ __launch_bounds__(256) void k_scanA(const int* __restrict__ cnt,
                                               int* __restrict__ bsum, int N) {
    __shared__ int s[256];
    int i = blockIdx.x * 256 + threadIdx.x;
    s[threadIdx.x] = (i < N) ? cnt[i] : 0;
    __syncthreads();
    for (int off = 128; off > 0; off >>= 1) {
        if (threadIdx.x < off) s[threadIdx.x] += s[threadIdx.x + off];
        __syncthreads();
    }
    if (threadIdx.x == 0) bsum[blockIdx.x] = s[0];
}

// ---------- 3. scan step B: exclusive scan of block sums (single block) ----------
__global__ __launch_bounds__(512) void k_scanB(int* __restrict__ bsum, int nb,
                                               int* __restrict__ row_ptr, int N, int E) {
    __shared__ int s[512];
    int t = threadIdx.x;
    int v = (t < nb) ? bsum[t] : 0;
    s[t] = v;
    __syncthreads();
    for (int off = 1; off < 512; off <<= 1) {
        int add = (t >= off) ? s[t - off] : 0;
        __syncthreads();
        s[t] += add;
        __syncthreads();
    }
    if (t < nb) bsum[t] = s[t] - v;     // exclusive
    if (t == 0) row_ptr[N] = E;
}

// ---------- 4. scan step C: row_ptr + dinv ----------
__global__ __launch_bounds__(256) void k_scanC(const int* __restrict__ cnt,
                                               const int* __restrict__ bsum,
                                               int* __restrict__ row_ptr,
                                               float* __restrict__ dinv, int N) {
    __shared__ int s[256];
    int i = blockIdx.x * 256 + threadIdx.x;
    int t = threadIdx.x;
    int c = (i < N) ? cnt[i] : 0;
    s[t] = c;
    __syncthreads();
    for (int off = 1; off < 256; off <<= 1) {
        int add = (t >= off) ? s[t - off] : 0;
        __syncthreads();
        s[t] += add;
        __syncthreads();
    }
    if (i < N) {
        row_ptr[i] = bsum[blockIdx.x] + s[t] - c;
        dinv[i] = rsqrtf((float)c + 1.0f);                 // +1 self-loop
    }
}

// ---------- 5. fill CSR bins: pack (src, dinv[src]) ----------
__global__ __launch_bounds__(256) void k_fill(const int* __restrict__ src,
                                              const int* __restrict__ dst,
                                              const int* __restrict__ row_ptr,
                                              const float* __restrict__ dinv,
                                              int* __restrict__ cursor,
                                              uint2* __restrict__ epk, int E) {
    int e = blockIdx.x * 256 + threadIdx.x;
    if (e >= E) return;
    int d = dst[e];
    int s = src[e];
    int pos = row_ptr[d] + atomicAdd(&cursor[d], 1);
    epk[pos] = make_uint2((unsigned)s, __float_as_uint(dinv[s]));
}

// ---------- 6. XW = x @ W, 4x4 register tile, bf16 output ----------
// block: 256 threads, 32 rows; thread (tx,ty): cols tx*4.., rows ty*4..
__global__ __launch_bounds__(256) void k_gemm(const float* __restrict__ x,
                                              const float* __restrict__ W,
                                              unsigned short* __restrict__ xwb, int N) {
    __shared__ float Ws[CH][CH];   // 64 KiB
    __shared__ float xs[32][CH];   // 16 KiB
    int t = threadIdx.x;
    {
        const float4* W4 = (const float4*)W;
        float4* Ws4 = (float4*)(&Ws[0][0]);
        #pragma unroll
        for (int i = 0; i < 16; ++i) Ws4[t + i * 256] = W4[t + i * 256];
    }
    int row0 = blockIdx.x * 32;
    {
        #pragma unroll
        for (int i = 0; i < 4; ++i) {
            int idx = t + i * 256;          // 1024 float4 total
            int r   = idx >> 5;
            int c4  = idx & 31;
            int row = row0 + r;
            float4 v = make_float4(0.f, 0.f, 0.f, 0.f);
            if (row < N) v = ((const float4*)(x + (size_t)row * CH))[c4];
            ((float4*)(&xs[r][0]))[c4] = v;
        }
    }
    __syncthreads();
    int tx = t & 31;
    int ty = t >> 5;
    float4 acc[4];
    #pragma unroll
    for (int r = 0; r < 4; ++r) acc[r] = make_float4(0.f, 0.f, 0.f, 0.f);

    for (int k = 0; k < CH; ++k) {
        float4 w = ((const float4*)(&Ws[k][0]))[tx];
        #pragma unroll
        for (int r = 0; r < 4; ++r) {
            float xv = xs[ty * 4 + r][k];
            acc[r].x = fmaf(xv, w.x, acc[r].x);
            acc[r].y = fmaf(xv, w.y, acc[r].y);
            acc[r].z = fmaf(xv, w.z, acc[r].z);
            acc[r].w = fmaf(xv, w.w, acc[r].w);
        }
    }
    #pragma unroll
    for (int r = 0; r < 4; ++r) {
        int row = row0 + ty * 4 + r;
        if (row < N) {
            uint2 p;
            p.x = (unsigned)f2bf(acc[r].x) | ((unsigned)f2bf(acc[r].y) << 16);
            p.y = (unsigned)f2bf(acc[r].z) | ((unsigned)f2bf(acc[r].w) << 16);
            ((uint2*)(xwb + (size_t)row * CH))[tx] = p;
        }
    }
}

// ---------- 7. fused gather + self-loop + bias + ReLU ----------
// one 64-lane wave per destination node; 2 bf16 channels per lane
__global__ __launch_bounds__(256) void k_gather(const int* __restrict__ row_ptr,
                                                const uint2* __restrict__ epk,
                                                const unsigned short* __restrict__ xwb,
                                                const float* __restrict__ dinv,
                                                const float* __restrict__ bias,
                                                float* __restrict__ out, int N) {
    int n = blockIdx.x * 4 + (threadIdx.x >> 6);
    if (n >= N) return;
    int lane = threadIdx.x & 63;
    int beg = row_ptr[n];
    int end = row_ptr[n + 1];
    float2 acc = make_float2(0.f, 0.f);
    for (int p0 = beg; p0 < end; p0 += 64) {
        int m = end - p0; if (m > 64) m = 64;
        uint2 pk = make_uint2(0u, 0u);
        if (lane < m) pk = epk[p0 + lane];                 // coalesced batch load
        int   myi = (int)pk.x;
        float myn = __uint_as_float(pk.y);                 // 0.0f for idle lanes
        for (int j = 0; j < m; ++j) {
            int   s  = __shfl(myi, j);
            float ns = __shfl(myn, j);
            unsigned u = ((const unsigned*)(xwb + (size_t)s * CH))[lane];
            float a = __uint_as_float(u << 16);
            float b = __uint_as_float(u & 0xffff0000u);
            acc.x = fmaf(a, ns, acc.x);
            acc.y = fmaf(b, ns, acc.y);
        }
    }
    float dn = dinv[n];
    {
        unsigned u = ((const unsigned*)(xwb + (size_t)n * CH))[lane];   // self-loop
        float a = __uint_as_float(u << 16);
        float b = __uint_as_float(u & 0xffff0000u);
        acc.x = fmaf(a, dn, acc.x);
        acc.y = fmaf(b, dn, acc.y);
    }
    float2 bb = ((const float2*)bias)[lane];
    float2 o;
    o.x = fmaxf(fmaf(acc.x, dn, bb.x), 0.f);
    o.y = fmaxf(fmaf(acc.y, dn, bb.y), 0.f);
    ((float2*)(out + (size_t)n * CH))[lane] = o;
}

extern "C" void kernel_launch(void* const* d_in, const int* in_sizes, int n_in,
                              void* d_out, int out_size, void* d_ws, size_t ws_size,
                              hipStream_t stream) {
    const float* x  = (const float*)d_in[0];
    const int*   ei = (const int*)d_in[1];
    const float* W  = (const float*)d_in[2];
    const float* b  = (const float*)d_in[3];

    int N = in_sizes[0] / CH;
    int E = in_sizes[1] / 2;
    const int* src = ei;
    const int* dst = ei + E;
    float* out = (float*)d_out;

    // workspace layout
    unsigned short* xwb = (unsigned short*)d_ws;              // N*CH bf16
    int*   cnt     = (int*)(xwb + (size_t)N * CH);            // N
    int*   cursor  = cnt + N;                                 // N
    int*   row_ptr = cursor + N;                              // N+2 (pad)
    float* dinv    = (float*)(row_ptr + N + 2);               // N
    int*   bsum    = (int*)(dinv + N);                        // 512
    uintptr_t ep   = ((uintptr_t)(bsum + 512) + 7) & ~(uintptr_t)7;
    uint2* epk     = (uint2*)ep;                              // E

    int nb = (N + 255) / 256;

    hipMemsetAsync(cnt, 0, (size_t)2 * N * sizeof(int), stream);   // cnt + cursor
    k_count<<<(E + 255) / 256, 256, 0, stream>>>(dst, cnt, E);
    k_scanA<<<nb, 256, 0, stream>>>(cnt, bsum, N);
    k_scanB<<<1, 512, 0, stream>>>(bsum, nb, row_ptr, N, E);
    k_scanC<<<nb, 256, 0, stream>>>(cnt, bsum, row_ptr, dinv, N);
    k_fill <<<(E + 255) / 256, 256, 0, stream>>>(src, dst, row_ptr, dinv, cursor, epk, E);
    k_gemm <<<(N + 31) / 32, 256, 0, stream>>>(x, W, xwb, N);
    k_gather<<<(N + 3) / 4, 256, 0, stream>>>(row_ptr, epk, xwb, dinv, b, out, N);
}

// Round 4
// 207.086 us; speedup vs baseline: 13.9825x; 1.5944x over previous
//
#include <hip/hip_runtime.h>

constexpr int CH = 128;      // IN_CH == OUT_CH == 128

typedef __attribute__((ext_vector_type(8))) short short8v;   // 8 bf16 (4 VGPRs)
typedef __attribute__((ext_vector_type(4))) float f32x4;     // 4 fp32 acc

__device__ __forceinline__ unsigned short f2bf(float f) {
    unsigned u = __float_as_uint(f);
    u = (u + 0x7fffu + ((u >> 16) & 1u)) >> 16;   // RTN-even
    return (unsigned short)u;
}

// ---------- 1. histogram of dst + per-edge sequence number ----------
__global__ __launch_bounds__(256) void k_count(const int* __restrict__ dst,
                                               int* __restrict__ cnt,
                                               int* __restrict__ seq, int E) {
    int e = blockIdx.x * 256 + threadIdx.x;
    if (e < E) seq[e] = atomicAdd(&cnt[dst[e]], 1);
}

// ---------- 2. scan step A: per-block sums ----------
__global__ __launch_bounds__(256) void k_scanA(const int* __restrict__ cnt,
                                               int* __restrict__ bsum, int N) {
    __shared__ int s[256];
    int i = blockIdx.x * 256 + threadIdx.x;
    s[threadIdx.x] = (i < N) ? cnt[i] : 0;
    __syncthreads();
    for (int off = 128; off > 0; off >>= 1) {
        if (threadIdx.x < off) s[threadIdx.x] += s[threadIdx.x + off];
        __syncthreads();
    }
    if (threadIdx.x == 0) bsum[blockIdx.x] = s[0];
}

// ---------- 3. scan step B: exclusive scan of block sums ----------
__global__ __launch_bounds__(512) void k_scanB(int* __restrict__ bsum, int nb,
                                               int* __restrict__ row_ptr, int N, int E) {
    __shared__ int s[512];
    int t = threadIdx.x;
    int v = (t < nb) ? bsum[t] : 0;
    s[t] = v;
    __syncthreads();
    for (int off = 1; off < 512; off <<= 1) {
        int add = (t >= off) ? s[t - off] : 0;
        __syncthreads();
        s[t] += add;
        __syncthreads();
    }
    if (t < nb) bsum[t] = s[t] - v;     // exclusive
    if (t == 0) row_ptr[N] = E;
}

// ---------- 4. scan step C: row_ptr + dinv ----------
__global__ __launch_bounds__(256) void k_scanC(const int* __restrict__ cnt,
                                               const int* __restrict__ bsum,
                                               int* __restrict__ row_ptr,
                                               float* __restrict__ dinv, int N) {
    __shared__ int s[256];
    int i = blockIdx.x * 256 + threadIdx.x;
    int t = threadIdx.x;
    int c = (i < N) ? cnt[i] : 0;
    s[t] = c;
    __syncthreads();
    for (int off = 1; off < 256; off <<= 1) {
        int add = (t >= off) ? s[t - off] : 0;
        __syncthreads();
        s[t] += add;
        __syncthreads();
    }
    if (i < N) {
        row_ptr[i] = bsum[blockIdx.x] + s[t] - c;
        dinv[i] = rsqrtf((float)c + 1.0f);                 // +1 self-loop
    }
}

// ---------- 5. fill CSR bins (no atomics): pack (src, dinv[src]) ----------
__global__ __launch_bounds__(256) void k_fill(const int* __restrict__ src,
                                              const int* __restrict__ dst,
                                              const int* __restrict__ seq,
                                              const int* __restrict__ row_ptr,
                                              const float* __restrict__ dinv,
                                              uint2* __restrict__ epk, int E) {
    int e = blockIdx.x * 256 + threadIdx.x;
    if (e >= E) return;
    int d = dst[e];
    int s = src[e];
    int pos = row_ptr[d] + seq[e];
    epk[pos] = make_uint2((unsigned)s, __float_as_uint(dinv[s]));
}

// ---------- 6. XW = x @ W via MFMA bf16 (swizzled LDS), bf16 output ----------
// block = 256 thr (4 waves); tile 64 rows x 128 cols; K = 128 in 4 chunks of 32
__global__ __launch_bounds__(256) void k_gemm(const float* __restrict__ x,
                                              const float* __restrict__ W,
                                              unsigned short* __restrict__ xwb, int N) {
    __shared__ __align__(16) unsigned short Wt[CH * CH];   // W^T bf16, swizzled (32 KB)
    __shared__ __align__(16) unsigned short xs[64 * CH];   // x tile bf16, swizzled (16 KB)
    int t = threadIdx.x;
    int row0 = blockIdx.x * 64;

    // stage Wt[col][k] = bf16(W[k][col]); swizzle byte ^= (col&7)<<4
    #pragma unroll
    for (int i = 0; i < 32; ++i) {
        int idx = i * 256 + t;          // 0..8191 (pairs of k)
        int c  = idx & 127;
        int k2 = (idx >> 7) * 2;
        float w0 = W[(size_t)k2 * CH + c];
        float w1 = W[(size_t)(k2 + 1) * CH + c];
        unsigned pk = (unsigned)f2bf(w0) | ((unsigned)f2bf(w1) << 16);
        unsigned bo = ((unsigned)((c * CH + k2) * 2)) ^ ((unsigned)(c & 7) << 4);
        *(unsigned*)((char*)Wt + bo) = pk;
    }
    // stage xs[r][k] = bf16(x[row0+r][k]); swizzle byte ^= (r&7)<<4
    #pragma unroll
    for (int i = 0; i < 8; ++i) {
        int idx = i * 256 + t;          // 0..2047 float4-granules
        int r  = idx >> 5;
        int c4 = idx & 31;
        float4 v = make_float4(0.f, 0.f, 0.f, 0.f);
        int row = row0 + r;
        if (row < N) v = ((const float4*)(x + (size_t)row * CH))[c4];
        uint2 pk;
        pk.x = (unsigned)f2bf(v.x) | ((unsigned)f2bf(v.y) << 16);
        pk.y = (unsigned)f2bf(v.z) | ((unsigned)f2bf(v.w) << 16);
        unsigned bo = ((unsigned)((r * CH + c4 * 4) * 2)) ^ ((unsigned)(r & 7) << 4);
        *(uint2*)((char*)xs + bo) = pk;
    }
    __syncthreads();

    int w    = t >> 6;
    int lane = t & 63;
    int r16  = lane & 15;
    int kb   = (lane >> 4) << 3;        // 0,8,16,24

    f32x4 acc[8];
    #pragma unroll
    for (int f = 0; f < 8; ++f) acc[f] = (f32x4){0.f, 0.f, 0.f, 0.f};

    int arow = w * 16 + r16;
    #pragma unroll
    for (int kc = 0; kc < 4; ++kc) {
        unsigned abo = ((unsigned)((arow * CH + kc * 32 + kb) * 2)) ^ ((unsigned)(arow & 7) << 4);
        short8v a = *(const short8v*)((const char*)xs + abo);
        #pragma unroll
        for (int f = 0; f < 8; ++f) {
            int col = f * 16 + r16;
            unsigned bbo = ((unsigned)((col * CH + kc * 32 + kb) * 2)) ^ ((unsigned)(col & 7) << 4);
            short8v b = *(const short8v*)((const char*)Wt + bbo);
            acc[f] = __builtin_amdgcn_mfma_f32_16x16x32_bf16(a, b, acc[f], 0, 0, 0);
        }
    }

    // epilogue: acc -> xs (bf16, swizzled) -> coalesced global
    __syncthreads();
    #pragma unroll
    for (int f = 0; f < 8; ++f) {
        #pragma unroll
        for (int r = 0; r < 4; ++r) {
            int row_l = w * 16 + (lane >> 4) * 4 + r;   // C/D: row=(lane>>4)*4+reg
            int col   = f * 16 + r16;                   //      col=lane&15
            unsigned bo = ((unsigned)((row_l * CH + col) * 2)) ^ ((unsigned)(row_l & 7) << 4);
            *(unsigned short*)((char*)xs + bo) = f2bf(acc[f][r]);
        }
    }
    __syncthreads();
    #pragma unroll
    for (int i = 0; i < 4; ++i) {
        int g = i * 256 + t;            // 1024 granules of 16B
        int row_l = g >> 4;
        unsigned bo = ((unsigned)(g * 16)) ^ ((unsigned)(row_l & 7) << 4);
        uint4 v = *(const uint4*)((const char*)xs + bo);
        int row = row0 + row_l;
        if (row < N) ((uint4*)(xwb + (size_t)row * CH))[g & 15] = v;
    }
}

// ---------- 7. fused gather: 2 edges/iter (halves of the wave) ----------
__global__ __launch_bounds__(256) void k_gather(const int* __restrict__ row_ptr,
                                                const uint2* __restrict__ epk,
                                                const unsigned short* __restrict__ xwb,
                                                const float* __restrict__ dinv,
                                                const float* __restrict__ bias,
                                                float* __restrict__ out, int N) {
    int n = blockIdx.x * 4 + (threadIdx.x >> 6);
    if (n >= N) return;
    int lane = threadIdx.x & 63;
    int half = lane >> 5;
    int c8   = lane & 31;               // uint2 (4 bf16) column group
    int beg = row_ptr[n];
    int end = row_ptr[n + 1];
    float2 a0 = make_float2(0.f, 0.f), a1 = make_float2(0.f, 0.f);
    for (int p0 = beg; p0 < end; p0 += 64) {
        int m = end - p0; if (m > 64) m = 64;
        uint2 pk = make_uint2(0u, 0u);
        if (lane < m) pk = epk[p0 + lane];          // coalesced batch load
        int   myi = (int)pk.x;
        float myn = __uint_as_float(pk.y);          // 0.0f for idle lanes
        for (int j = 0; j < m; j += 2) {
            int jj = j + half;                      // low half: edge j, high: j+1
            int   s  = __shfl(myi, jj);             // jj==m (odd m) -> myn==0, safe
            float ns = __shfl(myn, jj);
            uint2 u = ((const uint2*)(xwb + (size_t)s * CH))[c8];
            a0.x = fmaf(__uint_as_float(u.x << 16),         ns, a0.x);
            a0.y = fmaf(__uint_as_float(u.x & 0xffff0000u), ns, a0.y);
            a1.x = fmaf(__uint_as_float(u.y << 16),         ns, a1.x);
            a1.y = fmaf(__uint_as_float(u.y & 0xffff0000u), ns, a1.y);
        }
    }
    a0.x += __shfl_xor(a0.x, 32);
    a0.y += __shfl_xor(a0.y, 32);
    a1.x += __shfl_xor(a1.x, 32);
    a1.y += __shfl_xor(a1.y, 32);
    if (half == 0) {
        float dn = dinv[n];
        uint2 u = ((const uint2*)(xwb + (size_t)n * CH))[c8];   // self-loop
        a0.x = fmaf(__uint_as_float(u.x << 16),         dn, a0.x);
        a0.y = fmaf(__uint_as_float(u.x & 0xffff0000u), dn, a0.y);
        a1.x = fmaf(__uint_as_float(u.y << 16),         dn, a1.x);
        a1.y = fmaf(__uint_as_float(u.y & 0xffff0000u), dn, a1.y);
        float4 bb = ((const float4*)bias)[c8];
        float4 o;
        o.x = fmaxf(fmaf(a0.x, dn, bb.x), 0.f);
        o.y = fmaxf(fmaf(a0.y, dn, bb.y), 0.f);
        o.z = fmaxf(fmaf(a1.x, dn, bb.z), 0.f);
        o.w = fmaxf(fmaf(a1.y, dn, bb.w), 0.f);
        ((float4*)(out + (size_t)n * CH))[c8] = o;
    }
}

extern "C" void kernel_launch(void* const* d_in, const int* in_sizes, int n_in,
                              void* d_out, int out_size, void* d_ws, size_t ws_size,
                              hipStream_t stream) {
    const float* x  = (const float*)d_in[0];
    const int*   ei = (const int*)d_in[1];
    const float* W  = (const float*)d_in[2];
    const float* b  = (const float*)d_in[3];

    int N = in_sizes[0] / CH;
    int E = in_sizes[1] / 2;
    const int* src = ei;
    const int* dst = ei + E;
    float* out = (float*)d_out;

    // workspace layout
    unsigned short* xwb = (unsigned short*)d_ws;              // N*CH bf16 (25.6 MB)
    uint2* epk     = (uint2*)(xwb + (size_t)N * CH);          // E uint2 (12.8 MB)
    int*   seq     = (int*)(epk + E);                         // E
    int*   cnt     = seq + E;                                 // N
    int*   row_ptr = cnt + N;                                 // N+2
    float* dinv    = (float*)(row_ptr + N + 2);               // N
    int*   bsum    = (int*)(dinv + N);                        // 512

    int nb = (N + 255) / 256;

    hipMemsetAsync(cnt, 0, (size_t)N * sizeof(int), stream);
    k_count<<<(E + 255) / 256, 256, 0, stream>>>(dst, cnt, seq, E);
    k_scanA<<<nb, 256, 0, stream>>>(cnt, bsum, N);
    k_scanB<<<1, 512, 0, stream>>>(bsum, nb, row_ptr, N, E);
    k_scanC<<<nb, 256, 0, stream>>>(cnt, bsum, row_ptr, dinv, N);
    k_fill <<<(E + 255) / 256, 256, 0, stream>>>(src, dst, seq, row_ptr, dinv, epk, E);
    k_gemm <<<(N + 63) / 64, 256, 0, stream>>>(x, W, xwb, N);
    k_gather<<<(N + 3) / 4, 256, 0, stream>>>(row_ptr, epk, xwb, dinv, b, out, N);
}